// Round 2
// baseline (506.088 us; speedup 1.0000x reference)
//
#include <hip/hip_runtime.h>
#include <stdint.h>

// Problem constants (fixed by reference setup_inputs)
#define B_ROWS 4096
#define D_DIM  512
#define K_CODES 16384
#define EPS 1e-6f

typedef __attribute__((ext_vector_type(8))) short short8;   // 8 bf16 (raw bits)
typedef __attribute__((ext_vector_type(4))) float floatx4;  // MFMA accumulator

__device__ __forceinline__ unsigned short f2bf(float f) {
  // round-to-nearest-even fp32 -> bf16 (inputs finite, no NaN handling)
  unsigned int u = __float_as_uint(f);
  u += 0x7FFFu + ((u >> 16) & 1u);
  return (unsigned short)(u >> 16);
}
__device__ __forceinline__ float bf2f(unsigned short h) {
  return __uint_as_float(((unsigned int)h) << 16);
}

__device__ __forceinline__ void load_lds16(const short* g, short* l) {
  // async global->LDS, 16B/lane; LDS dest = wave-uniform base + lane*16
  __builtin_amdgcn_global_load_lds(
      (const __attribute__((address_space(1))) void*)g,
      (__attribute__((address_space(3))) void*)l, 16, 0, 0);
}

// ---------------------------------------------------------------------------
// prep_x: x (4096x512 f32) -> A_cat (4096x1024 bf16: [x_hi | x_lo]) + row_term
// row_term[b] = sum(x^2) + 2*eps*sum(x) + D*eps^2.  Block 0 inits scalars.
// ---------------------------------------------------------------------------
__global__ void prep_x_kernel(const float* __restrict__ x,
                              short* __restrict__ A,
                              float* __restrict__ row_term,
                              float* __restrict__ loss_acc,
                              unsigned int* __restrict__ counter) {
  const int b = blockIdx.x;
  const int t = threadIdx.x;  // 64 threads = 1 wave
  if (b == 0 && t == 0) { loss_acc[0] = 0.0f; counter[0] = 0u; }
  const float* xr = x + (size_t)b * D_DIM;
  float4 v0 = ((const float4*)xr)[t * 2];
  float4 v1 = ((const float4*)xr)[t * 2 + 1];
  float vals[8] = {v0.x, v0.y, v0.z, v0.w, v1.x, v1.y, v1.z, v1.w};
  short8 hi, lo;
  float s = 0.f, q = 0.f;
#pragma unroll
  for (int i = 0; i < 8; ++i) {
    float v = vals[i];
    s += v;
    q += v * v;
    unsigned short h = f2bf(v);
    float r = v - bf2f(h);
    hi[i] = (short)h;
    lo[i] = (short)f2bf(r);
  }
  *(short8*)(A + (size_t)b * 1024 + t * 8) = hi;
  *(short8*)(A + (size_t)b * 1024 + 512 + t * 8) = lo;
#pragma unroll
  for (int m = 1; m < 64; m <<= 1) {
    s += __shfl_xor(s, m, 64);
    q += __shfl_xor(q, m, 64);
  }
  if (t == 0) row_term[b] = q + 2.0f * EPS * s + (float)D_DIM * EPS * EPS;
}

// ---------------------------------------------------------------------------
// prep_w (fused sums): w (512x16384 f32, D-major) -> W_cat (16384x1024 bf16:
// [w_hi | w_lo], K-major) + col_term[k] = sum_d(w^2) - 2*eps*sum_d(w).
// One block owns a 64-wide k-strip; loops over D in 64-chunks via LDS
// transpose (+1 pad, conflict-free). No atomics: col_term written once.
// ---------------------------------------------------------------------------
__global__ void prep_w_kernel(const float* __restrict__ w,
                              short* __restrict__ W,
                              float* __restrict__ col_term) {
  __shared__ float tile[64][65];
  __shared__ float red[2][64][4];
  const int k0 = blockIdx.x * 64;
  const int t = threadIdx.x;  // 256
  const int kl = t & 63;      // lane within wave = k-local for sum phase
  const int dg = t >> 6;      // wave id = d-group for sum phase
  float s = 0.f, q = 0.f;
  for (int d0 = 0; d0 < D_DIM; d0 += 64) {
    __syncthreads();  // protect tile reuse across d-chunks
#pragma unroll
    for (int i = 0; i < 16; ++i) {
      int idx = i * 256 + t;
      int r = idx >> 6, c = idx & 63;  // r: d-local, c: k-local (coalesced)
      tile[r][c] = w[(size_t)(d0 + r) * K_CODES + k0 + c];
    }
    __syncthreads();
    // sums: thread covers k=kl, d in [dg*16, dg*16+16); lane-consecutive k -> no conflict
#pragma unroll
    for (int j = 0; j < 16; ++j) {
      float v = tile[dg * 16 + j][kl];
      s += v;
      q += v * v;
    }
    // transposed hi/lo split write (K-major)
#pragma unroll
    for (int i = 0; i < 16; ++i) {
      int idx = i * 256 + t;
      int rk = idx >> 6, cd = idx & 63;  // rk: k-local, cd: d-local
      float v = tile[cd][rk];
      unsigned short h = f2bf(v);
      float r2 = v - bf2f(h);
      W[(size_t)(k0 + rk) * 1024 + d0 + cd] = (short)h;
      W[(size_t)(k0 + rk) * 1024 + 512 + d0 + cd] = (short)f2bf(r2);
    }
  }
  red[0][kl][dg] = s;
  red[1][kl][dg] = q;
  __syncthreads();
  if (t < 64) {
    float ss = red[0][t][0] + red[0][t][1] + red[0][t][2] + red[0][t][3];
    float qq = red[1][t][0] + red[1][t][1] + red[1][t][2] + red[1][t][3];
    col_term[k0 + t] = qq - 2.0f * EPS * ss;
  }
}

// ---------------------------------------------------------------------------
// som_gemm: C[b,k] = x[b]·w[:,k] via 3-term hi/lo bf16 MFMA (virtual K = 1536)
// fused epilogue: d2 -> packed (d2_bits<<32)|k -> per-row min over the 128-col
// tile -> partial[nTile][row]. Tiles 128x128, BK=64, 4 waves, 16x16x32 MFMA.
// LDS tiles XOR-swizzled: LDS(r, chunk j) = G(r, j^(r&7)); staging permutes
// the global source column per lane (dest is forced linear by global_load_lds)
// so fragment reads spread over all 32 banks at <=2-way aliasing (free).
// lds_min aliases As (dead after K-loop) -> 32KB LDS -> 5 blocks/CU.
// ---------------------------------------------------------------------------
__global__ __launch_bounds__(256, 5) void som_gemm_kernel(
    const short* __restrict__ A, const short* __restrict__ W,
    const float* __restrict__ row_term, const float* __restrict__ col_term,
    unsigned long long* __restrict__ partial) {
  __shared__ __align__(16) short As[128 * 64];
  __shared__ __align__(16) short Bs[128 * 64];

  const int nt = blockIdx.x;  // 0..127
  const int mt = blockIdx.y;  // 0..31
  const int m0 = mt * 128, n0 = nt * 128;
  const int tid = threadIdx.x;
  const int wv = tid >> 6, lane = tid & 63;
  const int m_off = (wv & 1) * 64, n_off = (wv >> 1) * 64;
  const int q = lane >> 4, l15 = lane & 15;

  floatx4 acc[4][4];
  const floatx4 zero = {0.f, 0.f, 0.f, 0.f};
#pragma unroll
  for (int mi = 0; mi < 4; ++mi)
#pragma unroll
    for (int ni = 0; ni < 4; ++ni) acc[mi][ni] = zero;

  const int srow = lane >> 3;                      // row within 8-row chunk
  const int scol = ((lane & 7) ^ (srow & 7)) * 8;  // XOR-swizzled source col

  for (int kt = 0; kt < 24; ++kt) {
    // virtual k' in [0,1536): terms hi*hi (kt 0..7), lo*hi (8..15), hi*lo (16..23)
    const int a_k0 = (kt * 64) & 1023;
    const int w_k0 = (kt < 16) ? ((kt * 64) & 511) : (kt * 64 - 512);
    __syncthreads();  // previous iter's ds_reads done before overwrite
#pragma unroll
    for (int i = 0; i < 4; ++i) {
      const int c = wv * 4 + i;  // chunk 0..15, covers rows c*8..c*8+7
      const int row = c * 8 + srow;
      load_lds16(A + (size_t)(m0 + row) * 1024 + a_k0 + scol, As + c * 512);
      load_lds16(W + (size_t)(n0 + row) * 1024 + w_k0 + scol, Bs + c * 512);
    }
    __syncthreads();  // waits vmcnt(0): staging complete
#pragma unroll
    for (int ks = 0; ks < 2; ++ks) {
      short8 af[4], bf[4];
#pragma unroll
      for (int mi = 0; mi < 4; ++mi)
        af[mi] = *(const short8*)(As + (m_off + mi * 16 + l15) * 64 +
                                  (((ks * 4 + q) ^ (l15 & 7)) * 8));
#pragma unroll
      for (int ni = 0; ni < 4; ++ni)
        bf[ni] = *(const short8*)(Bs + (n_off + ni * 16 + l15) * 64 +
                                  (((ks * 4 + q) ^ (l15 & 7)) * 8));
#pragma unroll
      for (int mi = 0; mi < 4; ++mi)
#pragma unroll
        for (int ni = 0; ni < 4; ++ni)
          acc[mi][ni] = __builtin_amdgcn_mfma_f32_16x16x32_bf16(
              af[mi], bf[ni], acc[mi][ni], 0, 0, 0);
    }
  }

  // epilogue: d2 = rt + ct - 2*cross; packed min (smallest d2, tie -> smallest k)
  float ct[4];
#pragma unroll
  for (int ni = 0; ni < 4; ++ni) ct[ni] = col_term[n0 + n_off + ni * 16 + l15];
  float rt[16];
#pragma unroll
  for (int mi = 0; mi < 4; ++mi)
#pragma unroll
    for (int r = 0; r < 4; ++r)
      rt[mi * 4 + r] = row_term[m0 + m_off + mi * 16 + q * 4 + r];

  __syncthreads();  // all waves done reading As before lds_min aliases it
  unsigned long long* lds_min = (unsigned long long*)As;  // [2][128]

#pragma unroll
  for (int mi = 0; mi < 4; ++mi) {
#pragma unroll
    for (int r = 0; r < 4; ++r) {
      unsigned long long v = ~0ull;
#pragma unroll
      for (int ni = 0; ni < 4; ++ni) {
        float d2 = rt[mi * 4 + r] + ct[ni] - 2.0f * acc[mi][ni][r];
        d2 = fmaxf(d2, 0.0f);  // >=0 so float bit order == value order
        unsigned long long p =
            ((unsigned long long)__float_as_uint(d2) << 32) |
            (unsigned int)(n0 + n_off + ni * 16 + l15);
        v = p < v ? p : v;
      }
#pragma unroll
      for (int mms = 1; mms < 16; mms <<= 1) {
        unsigned long long o = __shfl_xor(v, mms, 64);
        v = o < v ? o : v;
      }
      if (l15 == 0) lds_min[(wv >> 1) * 128 + m_off + mi * 16 + q * 4 + r] = v;
    }
  }
  __syncthreads();
  if (tid < 128) {
    unsigned long long v0 = lds_min[tid];
    unsigned long long v1 = lds_min[128 + tid];
    partial[(size_t)nt * B_ROWS + m0 + tid] = v1 < v0 ? v1 : v0;
  }
}

// ---------------------------------------------------------------------------
// finalize: per-row min over 128 N-tiles, sqrt, gather locations, loss;
// last-arriving block writes the final mean loss (fused, arrival counter).
// ---------------------------------------------------------------------------
__global__ void finalize_kernel(const unsigned long long* __restrict__ partial,
                                const float* __restrict__ loc,
                                float* __restrict__ out,
                                float* __restrict__ loss_acc,
                                unsigned int* __restrict__ counter) {
  const int b = blockIdx.x * 256 + threadIdx.x;
  unsigned long long v = ~0ull;
  for (int nt = 0; nt < 128; ++nt) {
    unsigned long long p = partial[(size_t)nt * B_ROWS + b];
    v = p < v ? p : v;
  }
  unsigned int k = (unsigned int)(v & 0xFFFFFFFFu);
  float d2 = __uint_as_float((unsigned int)(v >> 32));
  float dist = sqrtf(d2);
  out[2 * b] = loc[2 * k];
  out[2 * b + 1] = loc[2 * k + 1];
  float s = dist;
#pragma unroll
  for (int m = 1; m < 64; m <<= 1) s += __shfl_xor(s, m, 64);
  __shared__ float wsum[4];
  const int wv = threadIdx.x >> 6, lane = threadIdx.x & 63;
  if (lane == 0) wsum[wv] = s;
  __syncthreads();
  if (threadIdx.x == 0) {
    atomicAdd(loss_acc, wsum[0] + wsum[1] + wsum[2] + wsum[3]);
    __threadfence();
    unsigned int old = atomicAdd(counter, 1u);
    if (old == gridDim.x - 1) {
      __threadfence();
      float total = atomicAdd(loss_acc, 0.0f);  // coherent read-back
      out[2 * B_ROWS] = total * (1.0f / (float)B_ROWS);
    }
  }
}

// ---------------------------------------------------------------------------
// Workspace layout (bytes):
//   A_cat    4096*1024*2  =  8,388,608   @ 0
//   W_cat   16384*1024*2  = 33,554,432   @ 8,388,608
//   row_term  4096*4      =     16,384   @ 41,943,040
//   col_term 16384*4      =     65,536   @ 41,959,424
//   partial 128*4096*8    =  4,194,304   @ 42,024,960
//   loss_acc 4                           @ 46,219,264
//   counter  4                           @ 46,219,268
// total ~46.2 MB
// ---------------------------------------------------------------------------
extern "C" void kernel_launch(void* const* d_in, const int* in_sizes, int n_in,
                              void* d_out, int out_size, void* d_ws, size_t ws_size,
                              hipStream_t stream) {
  const float* x = (const float*)d_in[0];
  const float* w = (const float*)d_in[1];
  const float* loc = (const float*)d_in[2];
  float* out = (float*)d_out;
  char* ws = (char*)d_ws;

  short* A = (short*)(ws + 0);
  short* W = (short*)(ws + 8388608);
  float* row_term = (float*)(ws + 41943040);
  float* col_term = (float*)(ws + 41959424);
  unsigned long long* partial = (unsigned long long*)(ws + 42024960);
  float* loss_acc = (float*)(ws + 46219264);
  unsigned int* counter = (unsigned int*)(ws + 46219268);

  prep_x_kernel<<<B_ROWS, 64, 0, stream>>>(x, A, row_term, loss_acc, counter);
  prep_w_kernel<<<K_CODES / 64, 256, 0, stream>>>(w, W, col_term);
  som_gemm_kernel<<<dim3(K_CODES / 128, B_ROWS / 128), 256, 0, stream>>>(
      A, W, row_term, col_term, partial);
  finalize_kernel<<<B_ROWS / 256, 256, 0, stream>>>(partial, loc, out, loss_acc,
                                                    counter);
}

// Round 3
// 303.622 us; speedup vs baseline: 1.6668x; 1.6668x over previous
//
#include <hip/hip_runtime.h>
#include <stdint.h>

// Problem constants (fixed by reference setup_inputs)
#define B_ROWS 4096
#define D_DIM  512
#define K_CODES 16384
#define EPS 1e-6f

typedef __attribute__((ext_vector_type(8))) short short8;   // 8 bf16 (raw bits)
typedef __attribute__((ext_vector_type(4))) float floatx4;  // MFMA accumulator

__device__ __forceinline__ unsigned short f2bf(float f) {
  // round-to-nearest-even fp32 -> bf16 (inputs finite, no NaN handling)
  unsigned int u = __float_as_uint(f);
  u += 0x7FFFu + ((u >> 16) & 1u);
  return (unsigned short)(u >> 16);
}
__device__ __forceinline__ float bf2f(unsigned short h) {
  return __uint_as_float(((unsigned int)h) << 16);
}

__device__ __forceinline__ void load_lds16(const short* g, short* l) {
  // async global->LDS, 16B/lane; LDS dest = wave-uniform base + lane*16
  __builtin_amdgcn_global_load_lds(
      (const __attribute__((address_space(1))) void*)g,
      (__attribute__((address_space(3))) void*)l, 16, 0, 0);
}

// ---------------------------------------------------------------------------
// prep_x: x (4096x512 f32) -> A_cat (4096x1024 bf16: [x_hi | x_lo]) + row_term
// row_term[b] = sum(x^2) + 2*eps*sum(x) + D*eps^2.  Block 0 inits scalars.
// ---------------------------------------------------------------------------
__global__ void prep_x_kernel(const float* __restrict__ x,
                              short* __restrict__ A,
                              float* __restrict__ row_term,
                              float* __restrict__ loss_acc,
                              unsigned int* __restrict__ counter) {
  const int b = blockIdx.x;
  const int t = threadIdx.x;  // 64 threads = 1 wave
  if (b == 0 && t == 0) { loss_acc[0] = 0.0f; counter[0] = 0u; }
  const float* xr = x + (size_t)b * D_DIM;
  float4 v0 = ((const float4*)xr)[t * 2];
  float4 v1 = ((const float4*)xr)[t * 2 + 1];
  float vals[8] = {v0.x, v0.y, v0.z, v0.w, v1.x, v1.y, v1.z, v1.w};
  short8 hi, lo;
  float s = 0.f, q = 0.f;
#pragma unroll
  for (int i = 0; i < 8; ++i) {
    float v = vals[i];
    s += v;
    q += v * v;
    unsigned short h = f2bf(v);
    float r = v - bf2f(h);
    hi[i] = (short)h;
    lo[i] = (short)f2bf(r);
  }
  *(short8*)(A + (size_t)b * 1024 + t * 8) = hi;
  *(short8*)(A + (size_t)b * 1024 + 512 + t * 8) = lo;
#pragma unroll
  for (int m = 1; m < 64; m <<= 1) {
    s += __shfl_xor(s, m, 64);
    q += __shfl_xor(q, m, 64);
  }
  if (t == 0) row_term[b] = q + 2.0f * EPS * s + (float)D_DIM * EPS * EPS;
}

// ---------------------------------------------------------------------------
// prep_w (fused sums): w (512x16384 f32, D-major) -> W_cat (16384x1024 bf16:
// [w_hi | w_lo], K-major) + col_term[k] = sum_d(w^2) - 2*eps*sum_d(w).
// One block owns a 64-wide k-strip; loops over D in 64-chunks via LDS
// transpose (+1 pad, conflict-free). No atomics: col_term written once
// (deterministic — atomics here could flip near-tie argmins).
// ---------------------------------------------------------------------------
__global__ void prep_w_kernel(const float* __restrict__ w,
                              short* __restrict__ W,
                              float* __restrict__ col_term) {
  __shared__ float tile[64][65];
  __shared__ float red[2][64][4];
  const int k0 = blockIdx.x * 64;
  const int t = threadIdx.x;  // 256
  const int kl = t & 63;      // lane within wave = k-local for sum phase
  const int dg = t >> 6;      // wave id = d-group for sum phase
  float s = 0.f, q = 0.f;
  for (int d0 = 0; d0 < D_DIM; d0 += 64) {
    __syncthreads();  // protect tile reuse across d-chunks
#pragma unroll
    for (int i = 0; i < 16; ++i) {
      int idx = i * 256 + t;
      int r = idx >> 6, c = idx & 63;  // r: d-local, c: k-local (coalesced)
      tile[r][c] = w[(size_t)(d0 + r) * K_CODES + k0 + c];
    }
    __syncthreads();
#pragma unroll
    for (int j = 0; j < 16; ++j) {
      float v = tile[dg * 16 + j][kl];
      s += v;
      q += v * v;
    }
#pragma unroll
    for (int i = 0; i < 16; ++i) {
      int idx = i * 256 + t;
      int rk = idx >> 6, cd = idx & 63;  // rk: k-local, cd: d-local
      float v = tile[cd][rk];
      unsigned short h = f2bf(v);
      float r2 = v - bf2f(h);
      W[(size_t)(k0 + rk) * 1024 + d0 + cd] = (short)h;
      W[(size_t)(k0 + rk) * 1024 + 512 + d0 + cd] = (short)f2bf(r2);
    }
  }
  red[0][kl][dg] = s;
  red[1][kl][dg] = q;
  __syncthreads();
  if (t < 64) {
    float ss = red[0][t][0] + red[0][t][1] + red[0][t][2] + red[0][t][3];
    float qq = red[1][t][0] + red[1][t][1] + red[1][t][2] + red[1][t][3];
    col_term[k0 + t] = qq - 2.0f * EPS * ss;
  }
}

// ---------------------------------------------------------------------------
// som_gemm: C[b,k] = x[b]·w[:,k] via 3-term hi/lo bf16 MFMA (virtual K = 1536)
// fused epilogue: d2 -> packed (d2_bits<<32)|k -> per-row min over the 128-col
// tile -> partial[nTile][row]. Tiles 128x128, BK=64, 4 waves, 16x16x32 MFMA.
// LDS tiles XOR-swizzled (R1->R2 cut SQ_LDS_BANK_CONFLICT 7.55e7 -> 0).
// lds_min aliases As (dead after K-loop) -> 32KB LDS.
// __launch_bounds__(256,3): budget 170 regs >= ~156 needed (64 AGPR acc + ~92
// VGPR). (256,5) in R2 capped at ~102 -> acc spilled to scratch, 123MB
// WRITE_SIZE, 446us. Do NOT raise the min-waves arg.
// ---------------------------------------------------------------------------
__global__ __launch_bounds__(256, 3) void som_gemm_kernel(
    const short* __restrict__ A, const short* __restrict__ W,
    const float* __restrict__ row_term, const float* __restrict__ col_term,
    unsigned long long* __restrict__ partial) {
  __shared__ __align__(16) short As[128 * 64];
  __shared__ __align__(16) short Bs[128 * 64];

  const int nt = blockIdx.x;  // 0..127
  const int mt = blockIdx.y;  // 0..31
  const int m0 = mt * 128, n0 = nt * 128;
  const int tid = threadIdx.x;
  const int wv = tid >> 6, lane = tid & 63;
  const int m_off = (wv & 1) * 64, n_off = (wv >> 1) * 64;
  const int q = lane >> 4, l15 = lane & 15;

  floatx4 acc[4][4];
  const floatx4 zero = {0.f, 0.f, 0.f, 0.f};
#pragma unroll
  for (int mi = 0; mi < 4; ++mi)
#pragma unroll
    for (int ni = 0; ni < 4; ++ni) acc[mi][ni] = zero;

  const int srow = lane >> 3;                      // row within 8-row chunk
  const int scol = ((lane & 7) ^ (srow & 7)) * 8;  // XOR-swizzled source col

  for (int kt = 0; kt < 24; ++kt) {
    // virtual k' in [0,1536): terms hi*hi (kt 0..7), lo*hi (8..15), hi*lo (16..23)
    const int a_k0 = (kt * 64) & 1023;
    const int w_k0 = (kt < 16) ? ((kt * 64) & 511) : (kt * 64 - 512);
    __syncthreads();  // previous iter's ds_reads done before overwrite
#pragma unroll
    for (int i = 0; i < 4; ++i) {
      const int c = wv * 4 + i;  // chunk 0..15, covers rows c*8..c*8+7
      const int row = c * 8 + srow;
      load_lds16(A + (size_t)(m0 + row) * 1024 + a_k0 + scol, As + c * 512);
      load_lds16(W + (size_t)(n0 + row) * 1024 + w_k0 + scol, Bs + c * 512);
    }
    __syncthreads();  // waits vmcnt(0): staging complete
#pragma unroll
    for (int ks = 0; ks < 2; ++ks) {
      short8 af[4], bf[4];
#pragma unroll
      for (int mi = 0; mi < 4; ++mi)
        af[mi] = *(const short8*)(As + (m_off + mi * 16 + l15) * 64 +
                                  (((ks * 4 + q) ^ (l15 & 7)) * 8));
#pragma unroll
      for (int ni = 0; ni < 4; ++ni)
        bf[ni] = *(const short8*)(Bs + (n_off + ni * 16 + l15) * 64 +
                                  (((ks * 4 + q) ^ (l15 & 7)) * 8));
#pragma unroll
      for (int mi = 0; mi < 4; ++mi)
#pragma unroll
        for (int ni = 0; ni < 4; ++ni)
          acc[mi][ni] = __builtin_amdgcn_mfma_f32_16x16x32_bf16(
              af[mi], bf[ni], acc[mi][ni], 0, 0, 0);
    }
  }

  // epilogue: d2 = rt + ct - 2*cross; packed min (smallest d2, tie -> smallest k)
  float ct[4];
#pragma unroll
  for (int ni = 0; ni < 4; ++ni) ct[ni] = col_term[n0 + n_off + ni * 16 + l15];
  float rt[16];
#pragma unroll
  for (int mi = 0; mi < 4; ++mi)
#pragma unroll
    for (int r = 0; r < 4; ++r)
      rt[mi * 4 + r] = row_term[m0 + m_off + mi * 16 + q * 4 + r];

  __syncthreads();  // all waves done reading As before lds_min aliases it
  unsigned long long* lds_min = (unsigned long long*)As;  // [2][128]

#pragma unroll
  for (int mi = 0; mi < 4; ++mi) {
#pragma unroll
    for (int r = 0; r < 4; ++r) {
      unsigned long long v = ~0ull;
#pragma unroll
      for (int ni = 0; ni < 4; ++ni) {
        float d2 = rt[mi * 4 + r] + ct[ni] - 2.0f * acc[mi][ni][r];
        d2 = fmaxf(d2, 0.0f);  // >=0 so float bit order == value order
        unsigned long long p =
            ((unsigned long long)__float_as_uint(d2) << 32) |
            (unsigned int)(n0 + n_off + ni * 16 + l15);
        v = p < v ? p : v;
      }
#pragma unroll
      for (int mms = 1; mms < 16; mms <<= 1) {
        unsigned long long o = __shfl_xor(v, mms, 64);
        v = o < v ? o : v;
      }
      if (l15 == 0) lds_min[(wv >> 1) * 128 + m_off + mi * 16 + q * 4 + r] = v;
    }
  }
  __syncthreads();
  if (tid < 128) {
    unsigned long long v0 = lds_min[tid];
    unsigned long long v1 = lds_min[128 + tid];
    partial[(size_t)nt * B_ROWS + m0 + tid] = v1 < v0 ? v1 : v0;
  }
}

// ---------------------------------------------------------------------------
// finalize: per-row min over 128 N-tiles (4 threads/row x 32 tiles), sqrt,
// gather locations, loss; last-arriving block writes the final mean loss.
// ---------------------------------------------------------------------------
__global__ void finalize_kernel(const unsigned long long* __restrict__ partial,
                                const float* __restrict__ loc,
                                float* __restrict__ out,
                                float* __restrict__ loss_acc,
                                unsigned int* __restrict__ counter) {
  __shared__ unsigned long long red[4][64];
  const int t = threadIdx.x;   // 256
  const int rl = t & 63;       // row-local
  const int p = t >> 6;        // partial-chunk 0..3
  const int b = blockIdx.x * 64 + rl;
  unsigned long long v = ~0ull;
#pragma unroll
  for (int i = 0; i < 32; ++i) {
    int nt = p * 32 + i;
    unsigned long long pv = partial[(size_t)nt * B_ROWS + b];
    v = pv < v ? pv : v;
  }
  red[p][rl] = v;
  __syncthreads();
  if (t < 64) {
    unsigned long long v0 = red[0][t], v1 = red[1][t];
    unsigned long long v2 = red[2][t], v3 = red[3][t];
    v0 = v1 < v0 ? v1 : v0;
    v2 = v3 < v2 ? v3 : v2;
    v0 = v2 < v0 ? v2 : v0;
    unsigned int k = (unsigned int)(v0 & 0xFFFFFFFFu);
    float d2 = __uint_as_float((unsigned int)(v0 >> 32));
    float dist = sqrtf(d2);
    int row = blockIdx.x * 64 + t;
    out[2 * row] = loc[2 * k];
    out[2 * row + 1] = loc[2 * k + 1];
    float s = dist;
#pragma unroll
    for (int m = 1; m < 64; m <<= 1) s += __shfl_xor(s, m, 64);
    if (t == 0) {
      atomicAdd(loss_acc, s);
      __threadfence();
      unsigned int old = atomicAdd(counter, 1u);
      if (old == gridDim.x - 1) {
        __threadfence();
        float total = atomicAdd(loss_acc, 0.0f);  // coherent read-back
        out[2 * B_ROWS] = total * (1.0f / (float)B_ROWS);
      }
    }
  }
}

// ---------------------------------------------------------------------------
// Workspace layout (bytes):
//   A_cat    4096*1024*2  =  8,388,608   @ 0
//   W_cat   16384*1024*2  = 33,554,432   @ 8,388,608
//   row_term  4096*4      =     16,384   @ 41,943,040
//   col_term 16384*4      =     65,536   @ 41,959,424
//   partial 128*4096*8    =  4,194,304   @ 42,024,960
//   loss_acc 4                           @ 46,219,264
//   counter  4                           @ 46,219,268
// total ~46.2 MB
// ---------------------------------------------------------------------------
extern "C" void kernel_launch(void* const* d_in, const int* in_sizes, int n_in,
                              void* d_out, int out_size, void* d_ws, size_t ws_size,
                              hipStream_t stream) {
  const float* x = (const float*)d_in[0];
  const float* w = (const float*)d_in[1];
  const float* loc = (const float*)d_in[2];
  float* out = (float*)d_out;
  char* ws = (char*)d_ws;

  short* A = (short*)(ws + 0);
  short* W = (short*)(ws + 8388608);
  float* row_term = (float*)(ws + 41943040);
  float* col_term = (float*)(ws + 41959424);
  unsigned long long* partial = (unsigned long long*)(ws + 42024960);
  float* loss_acc = (float*)(ws + 46219264);
  unsigned int* counter = (unsigned int*)(ws + 46219268);

  prep_x_kernel<<<B_ROWS, 64, 0, stream>>>(x, A, row_term, loss_acc, counter);
  prep_w_kernel<<<K_CODES / 64, 256, 0, stream>>>(w, W, col_term);
  som_gemm_kernel<<<dim3(K_CODES / 128, B_ROWS / 128), 256, 0, stream>>>(
      A, W, row_term, col_term, partial);
  finalize_kernel<<<B_ROWS / 64, 256, 0, stream>>>(partial, loc, out, loss_acc,
                                                   counter);
}

// Round 4
// 291.046 us; speedup vs baseline: 1.7389x; 1.0432x over previous
//
#include <hip/hip_runtime.h>
#include <stdint.h>

// Problem constants (fixed by reference setup_inputs)
#define B_ROWS 4096
#define D_DIM  512
#define K_CODES 16384
#define EPS 1e-6f

typedef __attribute__((ext_vector_type(8))) short short8;   // 8 bf16 (raw bits)
typedef __attribute__((ext_vector_type(4))) float floatx4;  // MFMA accumulator

__device__ __forceinline__ unsigned short f2bf(float f) {
  // round-to-nearest-even fp32 -> bf16 (inputs finite, no NaN handling)
  unsigned int u = __float_as_uint(f);
  u += 0x7FFFu + ((u >> 16) & 1u);
  return (unsigned short)(u >> 16);
}
__device__ __forceinline__ float bf2f(unsigned short h) {
  return __uint_as_float(((unsigned int)h) << 16);
}

__device__ __forceinline__ void load_lds16(const short* g, short* l) {
  // async global->LDS, 16B/lane; LDS dest = wave-uniform base + lane*16
  __builtin_amdgcn_global_load_lds(
      (const __attribute__((address_space(1))) void*)g,
      (__attribute__((address_space(3))) void*)l, 16, 0, 0);
}

// ---------------------------------------------------------------------------
// prep_x: x (4096x512 f32) -> A_cat (4096x1024 bf16: [x_hi | x_lo]) + row_term
// row_term[b] = sum(x^2) + 2*eps*sum(x) + D*eps^2.  Block 0 inits scalars.
// ---------------------------------------------------------------------------
__global__ void prep_x_kernel(const float* __restrict__ x,
                              short* __restrict__ A,
                              float* __restrict__ row_term,
                              float* __restrict__ loss_acc,
                              unsigned int* __restrict__ counter) {
  const int b = blockIdx.x;
  const int t = threadIdx.x;  // 64 threads = 1 wave
  if (b == 0 && t == 0) { loss_acc[0] = 0.0f; counter[0] = 0u; }
  const float* xr = x + (size_t)b * D_DIM;
  float4 v0 = ((const float4*)xr)[t * 2];
  float4 v1 = ((const float4*)xr)[t * 2 + 1];
  float vals[8] = {v0.x, v0.y, v0.z, v0.w, v1.x, v1.y, v1.z, v1.w};
  short8 hi, lo;
  float s = 0.f, q = 0.f;
#pragma unroll
  for (int i = 0; i < 8; ++i) {
    float v = vals[i];
    s += v;
    q += v * v;
    unsigned short h = f2bf(v);
    float r = v - bf2f(h);
    hi[i] = (short)h;
    lo[i] = (short)f2bf(r);
  }
  *(short8*)(A + (size_t)b * 1024 + t * 8) = hi;
  *(short8*)(A + (size_t)b * 1024 + 512 + t * 8) = lo;
#pragma unroll
  for (int m = 1; m < 64; m <<= 1) {
    s += __shfl_xor(s, m, 64);
    q += __shfl_xor(q, m, 64);
  }
  if (t == 0) row_term[b] = q + 2.0f * EPS * s + (float)D_DIM * EPS * EPS;
}

// ---------------------------------------------------------------------------
// prep_w: 2D grid (256 k-strips x 8 d-chunks = 2048 blocks, no serial d-loop;
// R3's 256-block serial version cost ~65us). 64x64 tile: float4 coalesced
// reads, LDS transpose (+1 pad), short8 (16B) vectorized hi/lo stores,
// per-(d-chunk,k) partial sums to colpart (reduced by col_reduce_kernel).
// ---------------------------------------------------------------------------
__global__ void prep_w_kernel(const float* __restrict__ w,
                              short* __restrict__ W,
                              float2* __restrict__ colpart) {
  __shared__ float tile[64][65];
  const int k0 = blockIdx.x * 64;
  const int d0 = blockIdx.y * 64;
  const int t = threadIdx.x;  // 256
#pragma unroll
  for (int i = 0; i < 4; ++i) {
    int idx = i * 256 + t;
    int r = idx >> 4, c4 = (idx & 15) * 4;  // r: d-local
    float4 v = *(const float4*)&w[(size_t)(d0 + r) * K_CODES + k0 + c4];
    tile[r][c4 + 0] = v.x;
    tile[r][c4 + 1] = v.y;
    tile[r][c4 + 2] = v.z;
    tile[r][c4 + 3] = v.w;
  }
  __syncthreads();
  const int sub = t & 7;        // d-subgroup within a k row
  const int cd8 = sub * 8;      // 8 consecutive d
#pragma unroll
  for (int g = 0; g < 2; ++g) {
    const int rk = (t >> 3) + g * 32;  // k-local 0..63
    short8 hi, lo;
    float s = 0.f, q = 0.f;
#pragma unroll
    for (int j = 0; j < 8; ++j) {
      float v = tile[cd8 + j][rk];
      s += v;
      q += v * v;
      unsigned short h = f2bf(v);
      float r2 = v - bf2f(h);
      hi[j] = (short)h;
      lo[j] = (short)f2bf(r2);
    }
    *(short8*)(W + (size_t)(k0 + rk) * 1024 + d0 + cd8) = hi;
    *(short8*)(W + (size_t)(k0 + rk) * 1024 + 512 + d0 + cd8) = lo;
    // reduce (s,q) across the 8 sub-lanes holding the same k
#pragma unroll
    for (int m = 1; m < 8; m <<= 1) {
      s += __shfl_xor(s, m, 64);
      q += __shfl_xor(q, m, 64);
    }
    if (sub == 0) colpart[(size_t)blockIdx.y * K_CODES + k0 + rk] = {s, q};
  }
}

// col_reduce: col_term[k] = sum_d(w^2) - 2*eps*sum_d(w) from 8 d-chunk partials
__global__ void col_reduce_kernel(const float2* __restrict__ colpart,
                                  float* __restrict__ col_term) {
  const int k = blockIdx.x * 256 + threadIdx.x;
  float s = 0.f, q = 0.f;
#pragma unroll
  for (int c = 0; c < 8; ++c) {
    float2 p = colpart[(size_t)c * K_CODES + k];
    s += p.x;
    q += p.y;
  }
  col_term[k] = q - 2.0f * EPS * s;
}

// ---------------------------------------------------------------------------
// som_gemm: C[b,k] = x[b]·w[:,k] via 3-term hi/lo bf16 MFMA (virtual K = 1536)
// fused epilogue -> packed (d2_bits<<32)|k per-row min -> partial[nt][row].
// R4 tile: 256x128 block, BK=64, 4 waves each 128x64 (acc 8x4 floatx4 = 128
// AGPR). LDS traffic/output -25% vs 128x128, half the barrier-drain events.
// XOR-swizzled LDS (R2: conflicts 7.55e7 -> 0). lds_min aliases As.
// __launch_bounds__(256,2): budget 256 regs for ~110 VGPR + 128 AGPR.
// (R2 lesson: min-waves too high -> acc spills to scratch, 123MB WRITE_SIZE.)
// ---------------------------------------------------------------------------
__global__ __launch_bounds__(256, 2) void som_gemm_kernel(
    const short* __restrict__ A, const short* __restrict__ W,
    const float* __restrict__ row_term, const float* __restrict__ col_term,
    unsigned long long* __restrict__ partial) {
  __shared__ __align__(16) short As[256 * 64];  // 32 KB
  __shared__ __align__(16) short Bs[128 * 64];  // 16 KB

  const int nt = blockIdx.x;  // 0..127
  const int mt = blockIdx.y;  // 0..15
  const int m0 = mt * 256, n0 = nt * 128;
  const int tid = threadIdx.x;
  const int wv = tid >> 6, lane = tid & 63;
  const int m_off = (wv & 1) * 128, n_off = (wv >> 1) * 64;
  const int q = lane >> 4, l15 = lane & 15;

  floatx4 acc[8][4];
  const floatx4 zero = {0.f, 0.f, 0.f, 0.f};
#pragma unroll
  for (int mi = 0; mi < 8; ++mi)
#pragma unroll
    for (int ni = 0; ni < 4; ++ni) acc[mi][ni] = zero;

  const int srow = lane >> 3;                      // row within 8-row chunk
  const int scol = ((lane & 7) ^ (srow & 7)) * 8;  // XOR-swizzled source col

  for (int kt = 0; kt < 24; ++kt) {
    // virtual k' in [0,1536): terms hi*hi (kt 0..7), lo*hi (8..15), hi*lo (16..23)
    const int a_k0 = (kt * 64) & 1023;
    const int w_k0 = (kt < 16) ? ((kt * 64) & 511) : (kt * 64 - 512);
    __syncthreads();  // previous iter's ds_reads done before overwrite
#pragma unroll
    for (int i = 0; i < 8; ++i) {  // As: 32 chunks of 8 rows, 8 per wave
      const int c = wv * 8 + i;
      load_lds16(A + (size_t)(m0 + c * 8 + srow) * 1024 + a_k0 + scol,
                 As + c * 512);
    }
#pragma unroll
    for (int i = 0; i < 4; ++i) {  // Bs: 16 chunks, 4 per wave
      const int c = wv * 4 + i;
      load_lds16(W + (size_t)(n0 + c * 8 + srow) * 1024 + w_k0 + scol,
                 Bs + c * 512);
    }
    __syncthreads();  // waits vmcnt(0): staging complete
#pragma unroll
    for (int ks = 0; ks < 2; ++ks) {
      const int sw = ((ks * 4 + q) ^ (l15 & 7)) * 8;
      short8 af[8], bf[4];
#pragma unroll
      for (int mi = 0; mi < 8; ++mi)
        af[mi] = *(const short8*)(As + (m_off + mi * 16 + l15) * 64 + sw);
#pragma unroll
      for (int ni = 0; ni < 4; ++ni)
        bf[ni] = *(const short8*)(Bs + (n_off + ni * 16 + l15) * 64 + sw);
#pragma unroll
      for (int mi = 0; mi < 8; ++mi)
#pragma unroll
        for (int ni = 0; ni < 4; ++ni)
          acc[mi][ni] = __builtin_amdgcn_mfma_f32_16x16x32_bf16(
              af[mi], bf[ni], acc[mi][ni], 0, 0, 0);
    }
  }

  // epilogue: d2 = rt + ct - 2*cross; packed min (smallest d2, tie -> smallest k)
  float ct[4];
#pragma unroll
  for (int ni = 0; ni < 4; ++ni) ct[ni] = col_term[n0 + n_off + ni * 16 + l15];

  __syncthreads();  // all waves done reading As before lds_min aliases it
  unsigned long long* lds_min = (unsigned long long*)As;  // [2][256]

#pragma unroll
  for (int mi = 0; mi < 8; ++mi) {
#pragma unroll
    for (int r = 0; r < 4; ++r) {
      const int row = m_off + mi * 16 + q * 4 + r;
      float rtv = row_term[m0 + row];
      unsigned long long v = ~0ull;
#pragma unroll
      for (int ni = 0; ni < 4; ++ni) {
        float d2 = rtv + ct[ni] - 2.0f * acc[mi][ni][r];
        d2 = fmaxf(d2, 0.0f);  // >=0 so float bit order == value order
        unsigned long long p =
            ((unsigned long long)__float_as_uint(d2) << 32) |
            (unsigned int)(n0 + n_off + ni * 16 + l15);
        v = p < v ? p : v;
      }
#pragma unroll
      for (int mms = 1; mms < 16; mms <<= 1) {
        unsigned long long o = __shfl_xor(v, mms, 64);
        v = o < v ? o : v;
      }
      if (l15 == 0) lds_min[(wv >> 1) * 256 + row] = v;
    }
  }
  __syncthreads();
  {
    unsigned long long v0 = lds_min[tid];
    unsigned long long v1 = lds_min[256 + tid];
    partial[(size_t)nt * B_ROWS + m0 + tid] = v1 < v0 ? v1 : v0;
  }
}

// ---------------------------------------------------------------------------
// finalize: per-row min over 128 N-tiles (4 threads/row x 32 tiles), sqrt,
// gather locations, loss; last-arriving block writes the final mean loss.
// ---------------------------------------------------------------------------
__global__ void finalize_kernel(const unsigned long long* __restrict__ partial,
                                const float* __restrict__ loc,
                                float* __restrict__ out,
                                float* __restrict__ loss_acc,
                                unsigned int* __restrict__ counter) {
  __shared__ unsigned long long red[4][64];
  const int t = threadIdx.x;   // 256
  const int rl = t & 63;       // row-local
  const int p = t >> 6;        // partial-chunk 0..3
  const int b = blockIdx.x * 64 + rl;
  unsigned long long v = ~0ull;
#pragma unroll
  for (int i = 0; i < 32; ++i) {
    int nt = p * 32 + i;
    unsigned long long pv = partial[(size_t)nt * B_ROWS + b];
    v = pv < v ? pv : v;
  }
  red[p][rl] = v;
  __syncthreads();
  if (t < 64) {
    unsigned long long v0 = red[0][t], v1 = red[1][t];
    unsigned long long v2 = red[2][t], v3 = red[3][t];
    v0 = v1 < v0 ? v1 : v0;
    v2 = v3 < v2 ? v3 : v2;
    v0 = v2 < v0 ? v2 : v0;
    unsigned int k = (unsigned int)(v0 & 0xFFFFFFFFu);
    float d2 = __uint_as_float((unsigned int)(v0 >> 32));
    float dist = sqrtf(d2);
    int row = blockIdx.x * 64 + t;
    out[2 * row] = loc[2 * k];
    out[2 * row + 1] = loc[2 * k + 1];
    float s = dist;
#pragma unroll
    for (int m = 1; m < 64; m <<= 1) s += __shfl_xor(s, m, 64);
    if (t == 0) {
      atomicAdd(loss_acc, s);
      __threadfence();
      unsigned int old = atomicAdd(counter, 1u);
      if (old == gridDim.x - 1) {
        __threadfence();
        float total = atomicAdd(loss_acc, 0.0f);  // coherent read-back
        out[2 * B_ROWS] = total * (1.0f / (float)B_ROWS);
      }
    }
  }
}

// ---------------------------------------------------------------------------
// Workspace layout (bytes):
//   A_cat    4096*1024*2  =  8,388,608   @ 0
//   W_cat   16384*1024*2  = 33,554,432   @ 8,388,608
//   row_term  4096*4      =     16,384   @ 41,943,040
//   col_term 16384*4      =     65,536   @ 41,959,424
//   partial 128*4096*8    =  4,194,304   @ 42,024,960
//     (colpart float2[8][16384] = 1 MB aliases partial: consumed by
//      col_reduce before som_gemm writes partial)
//   loss_acc 4                           @ 46,219,264
//   counter  4                           @ 46,219,268
// total ~46.2 MB
// ---------------------------------------------------------------------------
extern "C" void kernel_launch(void* const* d_in, const int* in_sizes, int n_in,
                              void* d_out, int out_size, void* d_ws, size_t ws_size,
                              hipStream_t stream) {
  const float* x = (const float*)d_in[0];
  const float* w = (const float*)d_in[1];
  const float* loc = (const float*)d_in[2];
  float* out = (float*)d_out;
  char* ws = (char*)d_ws;

  short* A = (short*)(ws + 0);
  short* W = (short*)(ws + 8388608);
  float* row_term = (float*)(ws + 41943040);
  float* col_term = (float*)(ws + 41959424);
  unsigned long long* partial = (unsigned long long*)(ws + 42024960);
  float2* colpart = (float2*)(ws + 42024960);  // aliases partial (see above)
  float* loss_acc = (float*)(ws + 46219264);
  unsigned int* counter = (unsigned int*)(ws + 46219268);

  prep_x_kernel<<<B_ROWS, 64, 0, stream>>>(x, A, row_term, loss_acc, counter);
  prep_w_kernel<<<dim3(K_CODES / 64, D_DIM / 64), 256, 0, stream>>>(w, W, colpart);
  col_reduce_kernel<<<K_CODES / 256, 256, 0, stream>>>(colpart, col_term);
  som_gemm_kernel<<<dim3(K_CODES / 128, B_ROWS / 256), 256, 0, stream>>>(
      A, W, row_term, col_term, partial);
  finalize_kernel<<<B_ROWS / 64, 256, 0, stream>>>(partial, loc, out, loss_acc,
                                                   counter);
}

// Round 5
// 288.947 us; speedup vs baseline: 1.7515x; 1.0073x over previous
//
#include <hip/hip_runtime.h>
#include <stdint.h>

// Problem constants (fixed by reference setup_inputs)
#define B_ROWS 4096
#define D_DIM  512
#define K_CODES 16384
#define EPS 1e-6f

typedef __attribute__((ext_vector_type(8))) short short8;   // 8 bf16 (raw bits)
typedef __attribute__((ext_vector_type(4))) float floatx4;  // MFMA accumulator

__device__ __forceinline__ unsigned short f2bf(float f) {
  // round-to-nearest-even fp32 -> bf16 (inputs finite, no NaN handling)
  unsigned int u = __float_as_uint(f);
  u += 0x7FFFu + ((u >> 16) & 1u);
  return (unsigned short)(u >> 16);
}
__device__ __forceinline__ float bf2f(unsigned short h) {
  return __uint_as_float(((unsigned int)h) << 16);
}

__device__ __forceinline__ void load_lds16(const short* g, short* l) {
  // async global->LDS, 16B/lane; LDS dest = wave-uniform base + lane*16
  __builtin_amdgcn_global_load_lds(
      (const __attribute__((address_space(1))) void*)g,
      (__attribute__((address_space(3))) void*)l, 16, 0, 0);
}

// ---------------------------------------------------------------------------
// prep (single launch; R4's 3 prep kernels fused, col_reduce eliminated):
//  blocks 0..2047  : w-tile path. w (512x16384 f32) -> W_cat (16384x1024 bf16
//                    [w_hi|w_lo], K-major) via 64x64 LDS transpose (+1 pad),
//                    float4 reads, short8 (16B) stores. Also writes per-chunk
//                    colpart[c][k] = sum_d(w^2) - 2*eps*sum_d(w) (8 d-chunks;
//                    summed by the gemm epilogue -- removes col_reduce launch,
//                    no atomics so col_term stays deterministic).
//  blocks 2048..2303: x path. x (4096x512) -> A_cat (4096x1024 [x_hi|x_lo]) +
//                    row_term[b] = sum(x^2)+2*eps*sum(x)+D*eps^2. One wave per
//                    row, 16 rows/block. Block 2048 inits loss/counter.
// ---------------------------------------------------------------------------
__global__ void prep_kernel(const float* __restrict__ x,
                            const float* __restrict__ w,
                            short* __restrict__ A, short* __restrict__ W,
                            float* __restrict__ row_term,
                            float* __restrict__ colpart,
                            float* __restrict__ loss_acc,
                            unsigned int* __restrict__ counter) {
  const int bid = blockIdx.x;
  const int t = threadIdx.x;  // 256
  if (bid < 2048) {
    __shared__ float tile[64][65];
    const int k0 = (bid & 255) * 64;
    const int dchunk = bid >> 8;  // 0..7
    const int d0 = dchunk * 64;
#pragma unroll
    for (int i = 0; i < 4; ++i) {
      int idx = i * 256 + t;
      int r = idx >> 4, c4 = (idx & 15) * 4;  // r: d-local
      float4 v = *(const float4*)&w[(size_t)(d0 + r) * K_CODES + k0 + c4];
      tile[r][c4 + 0] = v.x;
      tile[r][c4 + 1] = v.y;
      tile[r][c4 + 2] = v.z;
      tile[r][c4 + 3] = v.w;
    }
    __syncthreads();
    const int sub = t & 7;    // d-subgroup within a k row
    const int cd8 = sub * 8;  // 8 consecutive d
#pragma unroll
    for (int g = 0; g < 2; ++g) {
      const int rk = (t >> 3) + g * 32;  // k-local 0..63
      short8 hi, lo;
      float s = 0.f, q = 0.f;
#pragma unroll
      for (int j = 0; j < 8; ++j) {
        float v = tile[cd8 + j][rk];
        s += v;
        q += v * v;
        unsigned short h = f2bf(v);
        float r2 = v - bf2f(h);
        hi[j] = (short)h;
        lo[j] = (short)f2bf(r2);
      }
      *(short8*)(W + (size_t)(k0 + rk) * 1024 + d0 + cd8) = hi;
      *(short8*)(W + (size_t)(k0 + rk) * 1024 + 512 + d0 + cd8) = lo;
#pragma unroll
      for (int m = 1; m < 8; m <<= 1) {
        s += __shfl_xor(s, m, 64);
        q += __shfl_xor(q, m, 64);
      }
      if (sub == 0)
        colpart[(size_t)dchunk * K_CODES + k0 + rk] = q - 2.0f * EPS * s;
    }
  } else {
    const int xb = bid - 2048;  // 0..255
    if (xb == 0 && t == 0) { loss_acc[0] = 0.0f; counter[0] = 0u; }
    const int wv = t >> 6, lane = t & 63;
#pragma unroll
    for (int i = 0; i < 4; ++i) {
      const int b = xb * 16 + i * 4 + wv;  // one wave per row
      const float* xr = x + (size_t)b * D_DIM;
      float4 v0 = ((const float4*)xr)[lane * 2];
      float4 v1 = ((const float4*)xr)[lane * 2 + 1];
      float vals[8] = {v0.x, v0.y, v0.z, v0.w, v1.x, v1.y, v1.z, v1.w};
      short8 hi, lo;
      float s = 0.f, q = 0.f;
#pragma unroll
      for (int j = 0; j < 8; ++j) {
        float v = vals[j];
        s += v;
        q += v * v;
        unsigned short h = f2bf(v);
        float r = v - bf2f(h);
        hi[j] = (short)h;
        lo[j] = (short)f2bf(r);
      }
      *(short8*)(A + (size_t)b * 1024 + lane * 8) = hi;
      *(short8*)(A + (size_t)b * 1024 + 512 + lane * 8) = lo;
#pragma unroll
      for (int m = 1; m < 64; m <<= 1) {
        s += __shfl_xor(s, m, 64);
        q += __shfl_xor(q, m, 64);
      }
      if (lane == 0) row_term[b] = q + 2.0f * EPS * s + (float)D_DIM * EPS * EPS;
    }
  }
}

// ---------------------------------------------------------------------------
// som_gemm: C[b,k] = x[b]·w[:,k] via 3-term hi/lo bf16 MFMA (virtual K = 1536)
// fused epilogue -> packed (d2_bits<<32)|k per-row min -> partial[nt][row].
// R3 tile restored: 128x128, BK=64, 4 waves of 64x64 (R4's 256x128 regressed:
// 2 blocks/CU -> occupancy 22%, less barrier-drain overlap, 215us vs 210us).
// XOR-swizzled LDS (R2: conflicts 7.55e7 -> 0). lds_min aliases As.
// __launch_bounds__(256,4): R3 compiled to exactly 64 VGPR + 64 AGPR = 128 =
// the 4-waves/SIMD boundary; 32KB LDS x4 = 128 <= 160KB -> 4 blocks/CU.
// (R2 lesson: if budget too tight acc spills -> WRITE_SIZE balloons; revert
// to (256,3) if WRITE_SIZE >> 4MB.)
// ---------------------------------------------------------------------------
__global__ __launch_bounds__(256, 4) void som_gemm_kernel(
    const short* __restrict__ A, const short* __restrict__ W,
    const float* __restrict__ row_term, const float* __restrict__ colpart,
    unsigned long long* __restrict__ partial) {
  __shared__ __align__(16) short As[128 * 64];
  __shared__ __align__(16) short Bs[128 * 64];

  const int nt = blockIdx.x;  // 0..127
  const int mt = blockIdx.y;  // 0..31
  const int m0 = mt * 128, n0 = nt * 128;
  const int tid = threadIdx.x;
  const int wv = tid >> 6, lane = tid & 63;
  const int m_off = (wv & 1) * 64, n_off = (wv >> 1) * 64;
  const int q = lane >> 4, l15 = lane & 15;

  floatx4 acc[4][4];
  const floatx4 zero = {0.f, 0.f, 0.f, 0.f};
#pragma unroll
  for (int mi = 0; mi < 4; ++mi)
#pragma unroll
    for (int ni = 0; ni < 4; ++ni) acc[mi][ni] = zero;

  const int srow = lane >> 3;                      // row within 8-row chunk
  const int scol = ((lane & 7) ^ (srow & 7)) * 8;  // XOR-swizzled source col

  for (int kt = 0; kt < 24; ++kt) {
    // virtual k' in [0,1536): terms hi*hi (kt 0..7), lo*hi (8..15), hi*lo (16..23)
    const int a_k0 = (kt * 64) & 1023;
    const int w_k0 = (kt < 16) ? ((kt * 64) & 511) : (kt * 64 - 512);
    __syncthreads();  // previous iter's ds_reads done before overwrite
#pragma unroll
    for (int i = 0; i < 4; ++i) {
      const int c = wv * 4 + i;  // chunk 0..15, covers rows c*8..c*8+7
      const int row = c * 8 + srow;
      load_lds16(A + (size_t)(m0 + row) * 1024 + a_k0 + scol, As + c * 512);
      load_lds16(W + (size_t)(n0 + row) * 1024 + w_k0 + scol, Bs + c * 512);
    }
    __syncthreads();  // waits vmcnt(0): staging complete
#pragma unroll
    for (int ks = 0; ks < 2; ++ks) {
      const int sw = ((ks * 4 + q) ^ (l15 & 7)) * 8;
      short8 af[4], bf[4];
#pragma unroll
      for (int mi = 0; mi < 4; ++mi)
        af[mi] = *(const short8*)(As + (m_off + mi * 16 + l15) * 64 + sw);
#pragma unroll
      for (int ni = 0; ni < 4; ++ni)
        bf[ni] = *(const short8*)(Bs + (n_off + ni * 16 + l15) * 64 + sw);
#pragma unroll
      for (int mi = 0; mi < 4; ++mi)
#pragma unroll
        for (int ni = 0; ni < 4; ++ni)
          acc[mi][ni] = __builtin_amdgcn_mfma_f32_16x16x32_bf16(
              af[mi], bf[ni], acc[mi][ni], 0, 0, 0);
    }
  }

  // epilogue: ct[k] summed from the 8 d-chunk partials (L2-hot, deterministic)
  float ct[4];
#pragma unroll
  for (int ni = 0; ni < 4; ++ni) {
    const int k = n0 + n_off + ni * 16 + l15;
    float s = 0.f;
#pragma unroll
    for (int c = 0; c < 8; ++c) s += colpart[(size_t)c * K_CODES + k];
    ct[ni] = s;
  }
  float rt[16];
#pragma unroll
  for (int mi = 0; mi < 4; ++mi)
#pragma unroll
    for (int r = 0; r < 4; ++r)
      rt[mi * 4 + r] = row_term[m0 + m_off + mi * 16 + q * 4 + r];

  __syncthreads();  // all waves done reading As before lds_min aliases it
  unsigned long long* lds_min = (unsigned long long*)As;  // [2][128]

#pragma unroll
  for (int mi = 0; mi < 4; ++mi) {
#pragma unroll
    for (int r = 0; r < 4; ++r) {
      unsigned long long v = ~0ull;
#pragma unroll
      for (int ni = 0; ni < 4; ++ni) {
        float d2 = rt[mi * 4 + r] + ct[ni] - 2.0f * acc[mi][ni][r];
        d2 = fmaxf(d2, 0.0f);  // >=0 so float bit order == value order
        unsigned long long p =
            ((unsigned long long)__float_as_uint(d2) << 32) |
            (unsigned int)(n0 + n_off + ni * 16 + l15);
        v = p < v ? p : v;
      }
#pragma unroll
      for (int mms = 1; mms < 16; mms <<= 1) {
        unsigned long long o = __shfl_xor(v, mms, 64);
        v = o < v ? o : v;
      }
      if (l15 == 0) lds_min[(wv >> 1) * 128 + m_off + mi * 16 + q * 4 + r] = v;
    }
  }
  __syncthreads();
  if (tid < 128) {
    unsigned long long v0 = lds_min[tid];
    unsigned long long v1 = lds_min[128 + tid];
    partial[(size_t)nt * B_ROWS + m0 + tid] = v1 < v0 ? v1 : v0;
  }
}

// ---------------------------------------------------------------------------
// finalize: per-row min over 128 N-tiles (4 threads/row x 32 tiles), sqrt,
// gather locations, loss; last-arriving block writes the final mean loss.
// ---------------------------------------------------------------------------
__global__ void finalize_kernel(const unsigned long long* __restrict__ partial,
                                const float* __restrict__ loc,
                                float* __restrict__ out,
                                float* __restrict__ loss_acc,
                                unsigned int* __restrict__ counter) {
  __shared__ unsigned long long red[4][64];
  const int t = threadIdx.x;   // 256
  const int rl = t & 63;       // row-local
  const int p = t >> 6;        // partial-chunk 0..3
  const int b = blockIdx.x * 64 + rl;
  unsigned long long v = ~0ull;
#pragma unroll
  for (int i = 0; i < 32; ++i) {
    int nt = p * 32 + i;
    unsigned long long pv = partial[(size_t)nt * B_ROWS + b];
    v = pv < v ? pv : v;
  }
  red[p][rl] = v;
  __syncthreads();
  if (t < 64) {
    unsigned long long v0 = red[0][t], v1 = red[1][t];
    unsigned long long v2 = red[2][t], v3 = red[3][t];
    v0 = v1 < v0 ? v1 : v0;
    v2 = v3 < v2 ? v3 : v2;
    v0 = v2 < v0 ? v2 : v0;
    unsigned int k = (unsigned int)(v0 & 0xFFFFFFFFu);
    float d2 = __uint_as_float((unsigned int)(v0 >> 32));
    float dist = sqrtf(d2);
    int row = blockIdx.x * 64 + t;
    out[2 * row] = loc[2 * k];
    out[2 * row + 1] = loc[2 * k + 1];
    float s = dist;
#pragma unroll
    for (int m = 1; m < 64; m <<= 1) s += __shfl_xor(s, m, 64);
    if (t == 0) {
      atomicAdd(loss_acc, s);
      __threadfence();
      unsigned int old = atomicAdd(counter, 1u);
      if (old == gridDim.x - 1) {
        __threadfence();
        float total = atomicAdd(loss_acc, 0.0f);  // coherent read-back
        out[2 * B_ROWS] = total * (1.0f / (float)B_ROWS);
      }
    }
  }
}

// ---------------------------------------------------------------------------
// Workspace layout (bytes):
//   A_cat    4096*1024*2  =  8,388,608   @ 0
//   W_cat   16384*1024*2  = 33,554,432   @ 8,388,608
//   row_term  4096*4      =     16,384   @ 41,943,040
//   colpart  8*16384*4    =    524,288   @ 41,959,424  (own slot: gemm reads
//                                        it while writing partial -> no alias)
//   partial 128*4096*8    =  4,194,304   @ 42,483,712
//   loss_acc 4                           @ 46,678,016
//   counter  4                           @ 46,678,020
// total ~46.7 MB
// ---------------------------------------------------------------------------
extern "C" void kernel_launch(void* const* d_in, const int* in_sizes, int n_in,
                              void* d_out, int out_size, void* d_ws, size_t ws_size,
                              hipStream_t stream) {
  const float* x = (const float*)d_in[0];
  const float* w = (const float*)d_in[1];
  const float* loc = (const float*)d_in[2];
  float* out = (float*)d_out;
  char* ws = (char*)d_ws;

  short* A = (short*)(ws + 0);
  short* W = (short*)(ws + 8388608);
  float* row_term = (float*)(ws + 41943040);
  float* colpart = (float*)(ws + 41959424);
  unsigned long long* partial = (unsigned long long*)(ws + 42483712);
  float* loss_acc = (float*)(ws + 46678016);
  unsigned int* counter = (unsigned int*)(ws + 46678020);

  prep_kernel<<<2304, 256, 0, stream>>>(x, w, A, W, row_term, colpart,
                                        loss_acc, counter);
  som_gemm_kernel<<<dim3(K_CODES / 128, B_ROWS / 128), 256, 0, stream>>>(
      A, W, row_term, colpart, partial);
  finalize_kernel<<<B_ROWS / 64, 256, 0, stream>>>(partial, loc, out, loss_acc,
                                                   counter);
}